// Round 12
// baseline (284.216 us; speedup 1.0000x reference)
//
#include <hip/hip_runtime.h>
#include <hip/hip_bf16.h>
#include <cstdint>

#define B_ 2
#define S_ 2048
#define D_ 1024
#define H_ 16
#define HD_ 64

#define SCALE_LOG2 0.18033688011112042f   // (1/8) * log2(e), folded into Q proj

typedef __attribute__((ext_vector_type(8))) __bf16 bf16x8;
typedef __attribute__((ext_vector_type(8))) unsigned short ushort8;
typedef __attribute__((ext_vector_type(4))) unsigned short ushort4v;
typedef __attribute__((ext_vector_type(4))) float f32x4;

__device__ __forceinline__ unsigned short f2bf(float f) {
  __bf16 h = (__bf16)f;                       // native v_cvt (RNE)
  return __builtin_bit_cast(unsigned short, h);
}

__device__ __forceinline__ float bf2f(unsigned short u) {
  union { unsigned int i; float f; } v; v.i = ((unsigned int)u) << 16; return v.f;
}

__device__ __forceinline__ float fexp2(float x) {
#if __has_builtin(__builtin_amdgcn_exp2f)
  return __builtin_amdgcn_exp2f(x);           // raw v_exp_f32
#else
  return exp2f(x);
#endif
}

__device__ __forceinline__ f32x4 mfma16(bf16x8 a, bf16x8 b, f32x4 c) {
  return __builtin_amdgcn_mfma_f32_16x16x32_bf16(a, b, c, 0, 0, 0);
}

// LDS-hazard-only barrier: does NOT drain vmcnt, so in-flight global stores
// keep draining in the background.
#define LGKM_BARRIER()                                        \
  do {                                                        \
    asm volatile("s_waitcnt lgkmcnt(0)" ::: "memory");        \
    __builtin_amdgcn_s_barrier();                             \
  } while (0)

// ---------------------------------------------------------------------------
// Kernel A: QKV projections. C[m][n] = sum_k X[m][k] * W[n][k]  (NT GEMM)
// z=0: Q -> qh (PRE-SCALED by (1/8)*log2(e));  z=1: K -> kh;
// z=2: V -> vt[(b*H+h)*HD + hd][s] (transposed for PV B-operand).
// LDS pad 38 shorts (19 dw, odd): all fragment reads <=2-way bank aliasing
// (pad 40 = 20 dw gave bank=4(5c+g) mod 32 -> 8-way conflict on every read).
// ---------------------------------------------------------------------------
__global__ __launch_bounds__(256) void proj_qkv_kernel(
    const float* __restrict__ qin, const float* __restrict__ kin,
    const float* __restrict__ vin, const float* __restrict__ wq,
    const float* __restrict__ wk, const float* __restrict__ wv,
    unsigned short* __restrict__ qh, unsigned short* __restrict__ kh,
    unsigned short* __restrict__ vt)
{
  __shared__ unsigned short As[128][38];
  __shared__ unsigned short Bs[128][38];

  const int z = blockIdx.z;
  const float* X = (z == 0) ? qin : (z == 1) ? kin : vin;
  const float* W = (z == 0) ? wq : (z == 1) ? wk : wv;
  unsigned short* dst = (z == 0) ? qh : (z == 1) ? kh : vt;
  const float osc = (z == 0) ? SCALE_LOG2 : 1.0f;

  // bijective chunked XCD swizzle over the 256 (x,y) blocks
  const int lin = blockIdx.x + 8 * blockIdx.y;
  const int swz = (lin & 7) * 32 + (lin >> 3);
  const int bx = swz & 7, by = swz >> 3;

  const int tid = threadIdx.x;
  const int lane = tid & 63, wid = tid >> 6;
  const int c = lane & 15, g = lane >> 4;
  const int wr = wid >> 1, wc = wid & 1;           // 2x2 waves, 64x64 each
  const int m0 = by * 128, n0 = bx * 128;

  const int sr = tid >> 1, sh = tid & 1;
  const float* Ap = X + (size_t)(m0 + sr) * D_ + sh * 16;
  const float* Bp = W + (size_t)(n0 + sr) * D_ + sh * 16;

  float ar[16], br[16];
  f32x4 acc[4][4];
#pragma unroll
  for (int i = 0; i < 4; ++i)
#pragma unroll
    for (int j = 0; j < 4; ++j) acc[i][j] = (f32x4){0.f, 0.f, 0.f, 0.f};

  auto ldg_tile = [&](int kt) {
    const float* ap = Ap + kt * 32;
    const float* bp = Bp + kt * 32;
#pragma unroll
    for (int j = 0; j < 4; ++j) {
      *(f32x4*)(ar + 4 * j) = *(const f32x4*)(ap + 4 * j);
      *(f32x4*)(br + 4 * j) = *(const f32x4*)(bp + 4 * j);
    }
  };
  auto sts_tile = [&]() {
    unsigned short ta[16], tb[16];
#pragma unroll
    for (int j = 0; j < 16; ++j) { ta[j] = f2bf(ar[j]); tb[j] = f2bf(br[j]); }
    *(ushort8*)&As[sr][sh * 16]     = *(ushort8*)&ta[0];
    *(ushort8*)&As[sr][sh * 16 + 8] = *(ushort8*)&ta[8];
    *(ushort8*)&Bs[sr][sh * 16]     = *(ushort8*)&tb[0];
    *(ushort8*)&Bs[sr][sh * 16 + 8] = *(ushort8*)&tb[8];
  };

  ldg_tile(0);
  sts_tile();
  __syncthreads();

  for (int kt = 0; kt < 32; ++kt) {
    if (kt < 31) ldg_tile(kt + 1);
    bf16x8 af[4], bfr[4];
#pragma unroll
    for (int i = 0; i < 4; ++i) af[i]  = *(bf16x8*)&As[wr * 64 + i * 16 + c][g * 8];
#pragma unroll
    for (int i = 0; i < 4; ++i) bfr[i] = *(bf16x8*)&Bs[wc * 64 + i * 16 + c][g * 8];
#pragma unroll
    for (int mi = 0; mi < 4; ++mi)
#pragma unroll
      for (int ni = 0; ni < 4; ++ni)
        acc[mi][ni] = mfma16(af[mi], bfr[ni], acc[mi][ni]);
    __syncthreads();
    if (kt < 31) { sts_tile(); __syncthreads(); }
  }

#pragma unroll
  for (int mi = 0; mi < 4; ++mi) {
#pragma unroll
    for (int ni = 0; ni < 4; ++ni) {
      const int n = n0 + wc * 64 + ni * 16 + c;
      const int h = n >> 6, hd = n & 63;
      if (z < 2) {
#pragma unroll
        for (int r = 0; r < 4; ++r) {
          const int m = m0 + wr * 64 + mi * 16 + g * 4 + r;
          const int b = m >> 11, s = m & 2047;
          dst[((size_t)(b * H_ + h) * S_ + s) * HD_ + hd] = f2bf(acc[mi][ni][r] * osc);
        }
      } else {
        const int m = m0 + wr * 64 + mi * 16 + g * 4;
        const int b = m >> 11, s = m & 2047;
        ushort4v pk;
#pragma unroll
        for (int r = 0; r < 4; ++r) pk[r] = f2bf(acc[mi][ni][r]);
        *(ushort4v*)&dst[((size_t)(b * H_ + h) * HD_ + hd) * S_ + s] = pk;
      }
    }
  }
}

// ---------------------------------------------------------------------------
// Kernel B: attention == R7 structure (best, 232us) with ONE change: all LDS
// row strides repadded 72/88 -> 70 shorts (35 dw, odd mod 32).
// With 72 (36 dw = 4 mod 32) the K/V fragment reads hit bank 4(c+g) mod 32 ->
// 8-way conflict on EVERY b128 (the constant 3.1M SQ_LDS_BANK_CONFLICT).
// With 35 dw every access pattern here is <=2-way (free per m136):
//   frag reads: bank=(3c+4g) mod 32; staging writes: (3sr+8s3);
//   Ps write b64: (3c+2g); Ps row re-read: (3g+2c)+uniform.
// ---------------------------------------------------------------------------
__global__ __launch_bounds__(256) void attn_kernel(
    const unsigned short* __restrict__ qh, const unsigned short* __restrict__ kh,
    const unsigned short* __restrict__ vt, float* __restrict__ attn,
    unsigned short* __restrict__ comb)
{
  __shared__ unsigned short Ks[64][70];       // K tile [k][d]
  __shared__ unsigned short Vs[64][70];       // V^T tile [d][k]
  __shared__ unsigned short Ps[4][16][70];    // per-wave P tile [q][k]

  const int tid = threadIdx.x;
  const int lane = tid & 63, w = tid >> 6;
  const int c = lane & 15, g = lane >> 4;

  // bijective chunked XCD swizzle: XCD r gets bh in [4r, 4r+4)
  const int lin = blockIdx.x;
  const int swz = (lin & 7) * 128 + (lin >> 3);
  const int bh = swz >> 5;
  const int q0 = (swz & 31) * 64;

  const unsigned short* Qb = qh + (size_t)bh * S_ * HD_;
  const unsigned short* Kb = kh + (size_t)bh * S_ * HD_;
  const unsigned short* Vb = vt + (size_t)bh * HD_ * S_;
  float* attnb = attn + (size_t)bh * S_ * S_;

  const int sr = tid >> 2;            // staging row 0..63
  const int scol = (tid & 3) * 16;    // 0,16,32,48

  bf16x8 aQ[2];
#pragma unroll
  for (int t = 0; t < 2; ++t)
    aQ[t] = *(const bf16x8*)(Qb + (size_t)(q0 + w * 16 + c) * HD_ + t * 32 + g * 8);

  const unsigned short* Kst = Kb + (size_t)sr * HD_ + scol;
  const unsigned short* Vst = Vb + (size_t)sr * S_ + scol;

  // ---- pass 1: row expsums (per-lane over this lane's 16 k), LDS-staged K ----
  float l = 0.f;
  ushort8 kr0 = *(const ushort8*)Kst;
  ushort8 kr1 = *(const ushort8*)(Kst + 8);

  for (int kt = 0; kt < 32; ++kt) {
    *(ushort8*)&Ks[sr][scol]     = kr0;
    *(ushort8*)&Ks[sr][scol + 8] = kr1;
    LGKM_BARRIER();
    if (kt < 31) {
      const unsigned short* p = Kst + (size_t)(kt + 1) * 64 * HD_;
      kr0 = *(const ushort8*)p;
      kr1 = *(const ushort8*)(p + 8);
    }
#pragma unroll
    for (int ni = 0; ni < 4; ++ni) {
      f32x4 a = (f32x4){0.f, 0.f, 0.f, 0.f};
      a = mfma16(*(bf16x8*)&Ks[ni * 16 + c][g * 8],      aQ[0], a);
      a = mfma16(*(bf16x8*)&Ks[ni * 16 + c][32 + g * 8], aQ[1], a);
      l += (fexp2(a[0]) + fexp2(a[1])) + (fexp2(a[2]) + fexp2(a[3]));
    }
    LGKM_BARRIER();
  }
  l += __shfl_xor(l, 16);
  l += __shfl_xor(l, 32);
  const float invl = 1.f / l;

  // ---- pass 2: QK -> normalized P (bf16, Ps) -> PV; coalesced attn stores ----
  f32x4 ctx[4];
#pragma unroll
  for (int ni = 0; ni < 4; ++ni) ctx[ni] = (f32x4){0.f, 0.f, 0.f, 0.f};

  unsigned short* psrow = &Ps[w][c][g * 4];
  // store-phase lane roles: lane (c,g) stores row (q0+w*16+it*4+g), cols c*4..
  float* srow = attnb + (size_t)(q0 + w * 16 + g) * S_ + c * 4;

  kr0 = *(const ushort8*)Kst;
  kr1 = *(const ushort8*)(Kst + 8);
  ushort8 vr0 = *(const ushort8*)Vst;
  ushort8 vr1 = *(const ushort8*)(Vst + 8);

  for (int kt = 0; kt < 32; ++kt) {
    *(ushort8*)&Ks[sr][scol]     = kr0;
    *(ushort8*)&Ks[sr][scol + 8] = kr1;
    *(ushort8*)&Vs[sr][scol]     = vr0;
    *(ushort8*)&Vs[sr][scol + 8] = vr1;
    LGKM_BARRIER();
    if (kt < 31) {                       // prefetch BEFORE this tile's stores
      const unsigned short* p = Kst + (size_t)(kt + 1) * 64 * HD_;
      const unsigned short* q = Vst + (kt + 1) * 64;
      kr0 = *(const ushort8*)p;
      kr1 = *(const ushort8*)(p + 8);
      vr0 = *(const ushort8*)q;
      vr1 = *(const ushort8*)(q + 8);
    }

#pragma unroll
    for (int ni = 0; ni < 4; ++ni) {
      f32x4 a = (f32x4){0.f, 0.f, 0.f, 0.f};
      a = mfma16(*(bf16x8*)&Ks[ni * 16 + c][g * 8],      aQ[0], a);
      a = mfma16(*(bf16x8*)&Ks[ni * 16 + c][32 + g * 8], aQ[1], a);
      ushort4v pk;
#pragma unroll
      for (int r = 0; r < 4; ++r) pk[r] = f2bf(fexp2(a[r]) * invl);
      *(ushort4v*)(psrow + ni * 16) = pk;            // ds_write_b64 (per-wave)
    }

    bf16x8 aP[2];
#pragma unroll
    for (int t = 0; t < 2; ++t) aP[t] = *(bf16x8*)&Ps[w][c][t * 32 + g * 8];
#pragma unroll
    for (int ni = 0; ni < 4; ++ni)
#pragma unroll
      for (int t = 0; t < 2; ++t)
        ctx[ni] = mfma16(aP[t], *(bf16x8*)&Vs[ni * 16 + c][t * 32 + g * 8],
                         ctx[ni]);

    // coalesced attn store: re-read Ps row-major; 4 rows x 256B contiguous
#pragma unroll
    for (int it = 0; it < 4; ++it) {
      ushort4v pb = *(ushort4v*)&Ps[w][it * 4 + g][c * 4];
      f32x4 pf;
#pragma unroll
      for (int r = 0; r < 4; ++r) pf[r] = bf2f(pb[r]);
      __builtin_nontemporal_store(pf, (f32x4*)(srow + (size_t)it * 4 * S_ + kt * 64));
    }
    LGKM_BARRIER();
  }

  const int b = bh >> 4, h = bh & 15;
#pragma unroll
  for (int ni = 0; ni < 4; ++ni)
#pragma unroll
    for (int r = 0; r < 4; ++r)
      comb[(size_t)(b * S_ + q0 + w * 16 + g * 4 + r) * D_ + h * 64 + ni * 16 + c] =
          f2bf(ctx[ni][r]);
}

// ---------------------------------------------------------------------------
// Kernel C: output projection. out[m][n] = sum_k comb[m][k] * wo[n][k], f32 out.
// ---------------------------------------------------------------------------
__global__ __launch_bounds__(256) void out_proj_kernel(
    const unsigned short* __restrict__ comb, const float* __restrict__ wo,
    float* __restrict__ out)
{
  __shared__ unsigned short As[128][38];
  __shared__ unsigned short Bs[128][38];

  const int lin = blockIdx.x + 8 * blockIdx.y;
  const int swz = (lin & 7) * 32 + (lin >> 3);
  const int bx = swz & 7, by = swz >> 3;

  const int tid = threadIdx.x;
  const int lane = tid & 63, wid = tid >> 6;
  const int c = lane & 15, g = lane >> 4;
  const int wr = wid >> 1, wc = wid & 1;
  const int m0 = by * 128, n0 = bx * 128;
  const int sr = tid >> 1, sh = tid & 1;

  const unsigned short* Apb = comb + (size_t)(m0 + sr) * D_ + sh * 16;
  const float* Bpb = wo + (size_t)(n0 + sr) * D_ + sh * 16;

  ushort8 ar2[2];
  float br[16];
  f32x4 acc[4][4];
#pragma unroll
  for (int i = 0; i < 4; ++i)
#pragma unroll
    for (int j = 0; j < 4; ++j) acc[i][j] = (f32x4){0.f, 0.f, 0.f, 0.f};

  auto ldg_tile = [&](int kt) {
    ar2[0] = *(const ushort8*)(Apb + kt * 32);
    ar2[1] = *(const ushort8*)(Apb + kt * 32 + 8);
#pragma unroll
    for (int j = 0; j < 4; ++j)
      *(f32x4*)(br + 4 * j) = *(const f32x4*)(Bpb + kt * 32 + 4 * j);
  };
  auto sts_tile = [&]() {
    *(ushort8*)&As[sr][sh * 16]     = ar2[0];
    *(ushort8*)&As[sr][sh * 16 + 8] = ar2[1];
    unsigned short tb[16];
#pragma unroll
    for (int j = 0; j < 16; ++j) tb[j] = f2bf(br[j]);
    *(ushort8*)&Bs[sr][sh * 16]     = *(ushort8*)&tb[0];
    *(ushort8*)&Bs[sr][sh * 16 + 8] = *(ushort8*)&tb[8];
  };

  ldg_tile(0);
  sts_tile();
  __syncthreads();

  for (int kt = 0; kt < 32; ++kt) {
    if (kt < 31) ldg_tile(kt + 1);
    bf16x8 af[4], bfr[4];
#pragma unroll
    for (int i = 0; i < 4; ++i) af[i]  = *(bf16x8*)&As[wr * 64 + i * 16 + c][g * 8];
#pragma unroll
    for (int i = 0; i < 4; ++i) bfr[i] = *(bf16x8*)&Bs[wc * 64 + i * 16 + c][g * 8];
#pragma unroll
    for (int mi = 0; mi < 4; ++mi)
#pragma unroll
      for (int ni = 0; ni < 4; ++ni)
        acc[mi][ni] = mfma16(af[mi], bfr[ni], acc[mi][ni]);
    __syncthreads();
    if (kt < 31) { sts_tile(); __syncthreads(); }
  }

#pragma unroll
  for (int mi = 0; mi < 4; ++mi)
#pragma unroll
    for (int ni = 0; ni < 4; ++ni)
#pragma unroll
      for (int r = 0; r < 4; ++r) {
        const int m = m0 + wr * 64 + mi * 16 + g * 4 + r;
        const int n = n0 + wc * 64 + ni * 16 + c;
        out[(size_t)m * D_ + n] = acc[mi][ni][r];
      }
}

// ---------------------------------------------------------------------------
extern "C" void kernel_launch(void* const* d_in, const int* in_sizes, int n_in,
                              void* d_out, int out_size, void* d_ws, size_t ws_size,
                              hipStream_t stream)
{
  const float* q  = (const float*)d_in[0];
  const float* k  = (const float*)d_in[1];
  const float* v  = (const float*)d_in[2];
  const float* wq = (const float*)d_in[3];
  const float* wk = (const float*)d_in[4];
  const float* wv = (const float*)d_in[5];
  const float* wo = (const float*)d_in[6];

  float* out  = (float*)d_out;
  float* attn = out + (size_t)B_ * S_ * D_;   // tuple order: (out, attn)

  const size_t NE = (size_t)B_ * S_ * D_;
  unsigned short* qh   = (unsigned short*)d_ws;
  unsigned short* kh   = qh + NE;
  unsigned short* vt   = kh + NE;
  unsigned short* comb = vt + NE;

  proj_qkv_kernel<<<dim3(8, 32, 3), dim3(256), 0, stream>>>(q, k, v, wq, wk, wv, qh, kh, vt);
  attn_kernel<<<dim3(1024), dim3(256), 0, stream>>>(qh, kh, vt, attn, comb);
  out_proj_kernel<<<dim3(8, 32), dim3(256), 0, stream>>>(comb, wo, out);
}

// Round 13
// 232.615 us; speedup vs baseline: 1.2218x; 1.2218x over previous
//
#include <hip/hip_runtime.h>
#include <hip/hip_bf16.h>
#include <cstdint>

#define B_ 2
#define S_ 2048
#define D_ 1024
#define H_ 16
#define HD_ 64

#define SCALE_LOG2 0.18033688011112042f   // (1/8) * log2(e), folded into Q proj

typedef __attribute__((ext_vector_type(8))) __bf16 bf16x8;
typedef __attribute__((ext_vector_type(8))) unsigned short ushort8;
typedef __attribute__((ext_vector_type(4))) unsigned short ushort4v;
typedef __attribute__((ext_vector_type(4))) float f32x4;

__device__ __forceinline__ unsigned short f2bf(float f) {
  __bf16 h = (__bf16)f;                       // native v_cvt (RNE)
  return __builtin_bit_cast(unsigned short, h);
}

__device__ __forceinline__ float bf2f(unsigned short u) {
  union { unsigned int i; float f; } v; v.i = ((unsigned int)u) << 16; return v.f;
}

__device__ __forceinline__ float fexp2(float x) {
#if __has_builtin(__builtin_amdgcn_exp2f)
  return __builtin_amdgcn_exp2f(x);           // raw v_exp_f32
#else
  return exp2f(x);
#endif
}

__device__ __forceinline__ f32x4 mfma16(bf16x8 a, bf16x8 b, f32x4 c) {
  return __builtin_amdgcn_mfma_f32_16x16x32_bf16(a, b, c, 0, 0, 0);
}

// LDS-hazard-only barrier: does NOT drain vmcnt, so in-flight global stores
// keep draining in the background.
#define LGKM_BARRIER()                                        \
  do {                                                        \
    asm volatile("s_waitcnt lgkmcnt(0)" ::: "memory");        \
    __builtin_amdgcn_s_barrier();                             \
  } while (0)

// 32B-granule XOR swizzle for [64][64]-short LDS tiles (128B rows, NO pad):
// flips byte bits 5-6 only -> 16B alignment of every b128 chunk preserved,
// and both the fragment-read pattern (slot=(4t+g)^2(c&3): 8 lanes/16B slot
// = 2 lanes/bank) and the staging-write pattern (16 lanes/32B slot = 2/bank)
// are conflict-free (vs 8-way at the old aligned pad-72).
#define SWZ(r, sc) ((sc) ^ (((r) & 3) << 4))

// ---------------------------------------------------------------------------
// Kernel A: QKV projections. C[m][n] = sum_k X[m][k] * W[n][k]  (NT GEMM)
// z=0: Q -> qh[(b*H+h)*S + s][hd]  (PRE-SCALED by (1/8)*log2(e))
// z=1: K -> kh, same layout
// z=2: V -> vt[(b*H+h)*HD + hd][s]  (transposed for PV B-operand)
// ---------------------------------------------------------------------------
__global__ __launch_bounds__(256) void proj_qkv_kernel(
    const float* __restrict__ qin, const float* __restrict__ kin,
    const float* __restrict__ vin, const float* __restrict__ wq,
    const float* __restrict__ wk, const float* __restrict__ wv,
    unsigned short* __restrict__ qh, unsigned short* __restrict__ kh,
    unsigned short* __restrict__ vt)
{
  __shared__ unsigned short As[128][40];  // pad 40 (80B): 16B-aligned chunks
  __shared__ unsigned short Bs[128][40];

  const int z = blockIdx.z;
  const float* X = (z == 0) ? qin : (z == 1) ? kin : vin;
  const float* W = (z == 0) ? wq : (z == 1) ? wk : wv;
  unsigned short* dst = (z == 0) ? qh : (z == 1) ? kh : vt;
  const float osc = (z == 0) ? SCALE_LOG2 : 1.0f;

  // bijective chunked XCD swizzle over the 256 (x,y) blocks
  const int lin = blockIdx.x + 8 * blockIdx.y;
  const int swz = (lin & 7) * 32 + (lin >> 3);
  const int bx = swz & 7, by = swz >> 3;

  const int tid = threadIdx.x;
  const int lane = tid & 63, wid = tid >> 6;
  const int c = lane & 15, g = lane >> 4;
  const int wr = wid >> 1, wc = wid & 1;           // 2x2 waves, 64x64 each
  const int m0 = by * 128, n0 = bx * 128;

  const int sr = tid >> 1, sh = tid & 1;
  const float* Ap = X + (size_t)(m0 + sr) * D_ + sh * 16;
  const float* Bp = W + (size_t)(n0 + sr) * D_ + sh * 16;

  float ar[16], br[16];
  f32x4 acc[4][4];
#pragma unroll
  for (int i = 0; i < 4; ++i)
#pragma unroll
    for (int j = 0; j < 4; ++j) acc[i][j] = (f32x4){0.f, 0.f, 0.f, 0.f};

  auto ldg_tile = [&](int kt) {
    const float* ap = Ap + kt * 32;
    const float* bp = Bp + kt * 32;
#pragma unroll
    for (int j = 0; j < 4; ++j) {
      *(f32x4*)(ar + 4 * j) = *(const f32x4*)(ap + 4 * j);
      *(f32x4*)(br + 4 * j) = *(const f32x4*)(bp + 4 * j);
    }
  };
  auto sts_tile = [&]() {
    unsigned short ta[16], tb[16];
#pragma unroll
    for (int j = 0; j < 16; ++j) { ta[j] = f2bf(ar[j]); tb[j] = f2bf(br[j]); }
    *(ushort8*)&As[sr][sh * 16]     = *(ushort8*)&ta[0];
    *(ushort8*)&As[sr][sh * 16 + 8] = *(ushort8*)&ta[8];
    *(ushort8*)&Bs[sr][sh * 16]     = *(ushort8*)&tb[0];
    *(ushort8*)&Bs[sr][sh * 16 + 8] = *(ushort8*)&tb[8];
  };

  ldg_tile(0);
  sts_tile();
  __syncthreads();

  for (int kt = 0; kt < 32; ++kt) {
    if (kt < 31) ldg_tile(kt + 1);
    bf16x8 af[4], bfr[4];
#pragma unroll
    for (int i = 0; i < 4; ++i) af[i]  = *(bf16x8*)&As[wr * 64 + i * 16 + c][g * 8];
#pragma unroll
    for (int i = 0; i < 4; ++i) bfr[i] = *(bf16x8*)&Bs[wc * 64 + i * 16 + c][g * 8];
#pragma unroll
    for (int mi = 0; mi < 4; ++mi)
#pragma unroll
      for (int ni = 0; ni < 4; ++ni)
        acc[mi][ni] = mfma16(af[mi], bfr[ni], acc[mi][ni]);
    __syncthreads();
    if (kt < 31) { sts_tile(); __syncthreads(); }
  }

#pragma unroll
  for (int mi = 0; mi < 4; ++mi) {
#pragma unroll
    for (int ni = 0; ni < 4; ++ni) {
      const int n = n0 + wc * 64 + ni * 16 + c;
      const int h = n >> 6, hd = n & 63;
      if (z < 2) {
#pragma unroll
        for (int r = 0; r < 4; ++r) {
          const int m = m0 + wr * 64 + mi * 16 + g * 4 + r;
          const int b = m >> 11, s = m & 2047;
          dst[((size_t)(b * H_ + h) * S_ + s) * HD_ + hd] = f2bf(acc[mi][ni][r] * osc);
        }
      } else {
        const int m = m0 + wr * 64 + mi * 16 + g * 4;
        const int b = m >> 11, s = m & 2047;
        ushort4v pk;
#pragma unroll
        for (int r = 0; r < 4; ++r) pk[r] = f2bf(acc[mi][ni][r]);
        *(ushort4v*)&dst[((size_t)(b * H_ + h) * HD_ + hd) * S_ + s] = pk;
      }
    }
  }
}

// ---------------------------------------------------------------------------
// Kernel B: attention == R7 structure (best, 232us) with ONE change: Ks/Vs
// are unpadded [64][64] with the SWZ 32B XOR swizzle -> K/V b128 reads and
// staging writes go from 8-way bank conflict to conflict-free while keeping
// 16B alignment (R12's odd-pad killed the conflicts but broke alignment and
// regressed). Ps keeps R7's aligned 88-pad.
// Swapped QK^T (mfma(K,Q)); no-max softmax (scores bounded => exp2 safe;
// shift-invariant => exact); scale pre-folded into Q; coalesced attn stores
// re-read Ps row-major (256B contiguous per 16 lanes); lgkm-only barriers.
// ---------------------------------------------------------------------------
__global__ __launch_bounds__(256) void attn_kernel(
    const unsigned short* __restrict__ qh, const unsigned short* __restrict__ kh,
    const unsigned short* __restrict__ vt, float* __restrict__ attn,
    unsigned short* __restrict__ comb)
{
  __shared__ unsigned short Ks[64][64];       // K tile [k][d], SWZ-swizzled
  __shared__ unsigned short Vs[64][64];       // V^T tile [d][k], SWZ-swizzled
  __shared__ unsigned short Ps[4][16][88];    // per-wave P tile [q][k], pad 88

  const int tid = threadIdx.x;
  const int lane = tid & 63, w = tid >> 6;
  const int c = lane & 15, g = lane >> 4;

  // bijective chunked XCD swizzle: XCD r gets bh in [4r, 4r+4)
  const int lin = blockIdx.x;
  const int swz = (lin & 7) * 128 + (lin >> 3);
  const int bh = swz >> 5;
  const int q0 = (swz & 31) * 64;

  const unsigned short* Qb = qh + (size_t)bh * S_ * HD_;
  const unsigned short* Kb = kh + (size_t)bh * S_ * HD_;
  const unsigned short* Vb = vt + (size_t)bh * HD_ * S_;
  float* attnb = attn + (size_t)bh * S_ * S_;

  const int sr = tid >> 2;            // staging row 0..63
  const int scol = (tid & 3) * 16;    // 0,16,32,48
  const int swcol = SWZ(sr, scol);    // swizzled staging col (16B chunks keep +8)

  bf16x8 aQ[2];
#pragma unroll
  for (int t = 0; t < 2; ++t)
    aQ[t] = *(const bf16x8*)(Qb + (size_t)(q0 + w * 16 + c) * HD_ + t * 32 + g * 8);

  const unsigned short* Kst = Kb + (size_t)sr * HD_ + scol;
  const unsigned short* Vst = Vb + (size_t)sr * S_ + scol;

  // ---- pass 1: row expsums (per-lane over this lane's 16 k), LDS-staged K ----
  float l = 0.f;
  ushort8 kr0 = *(const ushort8*)Kst;
  ushort8 kr1 = *(const ushort8*)(Kst + 8);

  for (int kt = 0; kt < 32; ++kt) {
    *(ushort8*)&Ks[sr][swcol]     = kr0;
    *(ushort8*)&Ks[sr][swcol + 8] = kr1;
    LGKM_BARRIER();
    if (kt < 31) {
      const unsigned short* p = Kst + (size_t)(kt + 1) * 64 * HD_;
      kr0 = *(const ushort8*)p;
      kr1 = *(const ushort8*)(p + 8);
    }
#pragma unroll
    for (int ni = 0; ni < 4; ++ni) {
      f32x4 a = (f32x4){0.f, 0.f, 0.f, 0.f};
      a = mfma16(*(bf16x8*)&Ks[ni * 16 + c][SWZ(c, g * 8)],      aQ[0], a);
      a = mfma16(*(bf16x8*)&Ks[ni * 16 + c][SWZ(c, 32 + g * 8)], aQ[1], a);
      l += (fexp2(a[0]) + fexp2(a[1])) + (fexp2(a[2]) + fexp2(a[3]));
    }
    LGKM_BARRIER();
  }
  l += __shfl_xor(l, 16);
  l += __shfl_xor(l, 32);
  const float invl = 1.f / l;

  // ---- pass 2: QK -> normalized P (bf16, Ps) -> PV; coalesced attn stores ----
  f32x4 ctx[4];
#pragma unroll
  for (int ni = 0; ni < 4; ++ni) ctx[ni] = (f32x4){0.f, 0.f, 0.f, 0.f};

  unsigned short* psrow = &Ps[w][c][g * 4];
  // store-phase lane roles: lane (c,g) stores row (q0+w*16+it*4+g), cols c*4..
  float* srow = attnb + (size_t)(q0 + w * 16 + g) * S_ + c * 4;

  kr0 = *(const ushort8*)Kst;
  kr1 = *(const ushort8*)(Kst + 8);
  ushort8 vr0 = *(const ushort8*)Vst;
  ushort8 vr1 = *(const ushort8*)(Vst + 8);

  for (int kt = 0; kt < 32; ++kt) {
    *(ushort8*)&Ks[sr][swcol]     = kr0;
    *(ushort8*)&Ks[sr][swcol + 8] = kr1;
    *(ushort8*)&Vs[sr][swcol]     = vr0;
    *(ushort8*)&Vs[sr][swcol + 8] = vr1;
    LGKM_BARRIER();
    if (kt < 31) {                       // prefetch BEFORE this tile's stores
      const unsigned short* p = Kst + (size_t)(kt + 1) * 64 * HD_;
      const unsigned short* q = Vst + (kt + 1) * 64;
      kr0 = *(const ushort8*)p;
      kr1 = *(const ushort8*)(p + 8);
      vr0 = *(const ushort8*)q;
      vr1 = *(const ushort8*)(q + 8);
    }

#pragma unroll
    for (int ni = 0; ni < 4; ++ni) {
      f32x4 a = (f32x4){0.f, 0.f, 0.f, 0.f};
      a = mfma16(*(bf16x8*)&Ks[ni * 16 + c][SWZ(c, g * 8)],      aQ[0], a);
      a = mfma16(*(bf16x8*)&Ks[ni * 16 + c][SWZ(c, 32 + g * 8)], aQ[1], a);
      ushort4v pk;
#pragma unroll
      for (int r = 0; r < 4; ++r) pk[r] = f2bf(fexp2(a[r]) * invl);
      *(ushort4v*)(psrow + ni * 16) = pk;            // ds_write_b64 (per-wave)
    }

    bf16x8 aP[2];
#pragma unroll
    for (int t = 0; t < 2; ++t) aP[t] = *(bf16x8*)&Ps[w][c][t * 32 + g * 8];
#pragma unroll
    for (int ni = 0; ni < 4; ++ni)
#pragma unroll
      for (int t = 0; t < 2; ++t)
        ctx[ni] = mfma16(aP[t],
                         *(bf16x8*)&Vs[ni * 16 + c][SWZ(c, t * 32 + g * 8)],
                         ctx[ni]);

    // coalesced attn store: re-read Ps row-major; 4 rows x 256B contiguous
#pragma unroll
    for (int it = 0; it < 4; ++it) {
      ushort4v pb = *(ushort4v*)&Ps[w][it * 4 + g][c * 4];
      f32x4 pf;
#pragma unroll
      for (int r = 0; r < 4; ++r) pf[r] = bf2f(pb[r]);
      __builtin_nontemporal_store(pf, (f32x4*)(srow + (size_t)it * 4 * S_ + kt * 64));
    }
    LGKM_BARRIER();
  }

  const int b = bh >> 4, h = bh & 15;
#pragma unroll
  for (int ni = 0; ni < 4; ++ni)
#pragma unroll
    for (int r = 0; r < 4; ++r)
      comb[(size_t)(b * S_ + q0 + w * 16 + g * 4 + r) * D_ + h * 64 + ni * 16 + c] =
          f2bf(ctx[ni][r]);
}

// ---------------------------------------------------------------------------
// Kernel C: output projection. out[m][n] = sum_k comb[m][k] * wo[n][k], f32 out.
// ---------------------------------------------------------------------------
__global__ __launch_bounds__(256) void out_proj_kernel(
    const unsigned short* __restrict__ comb, const float* __restrict__ wo,
    float* __restrict__ out)
{
  __shared__ unsigned short As[128][40];
  __shared__ unsigned short Bs[128][40];

  const int lin = blockIdx.x + 8 * blockIdx.y;
  const int swz = (lin & 7) * 32 + (lin >> 3);
  const int bx = swz & 7, by = swz >> 3;

  const int tid = threadIdx.x;
  const int lane = tid & 63, wid = tid >> 6;
  const int c = lane & 15, g = lane >> 4;
  const int wr = wid >> 1, wc = wid & 1;
  const int m0 = by * 128, n0 = bx * 128;
  const int sr = tid >> 1, sh = tid & 1;

  const unsigned short* Apb = comb + (size_t)(m0 + sr) * D_ + sh * 16;
  const float* Bpb = wo + (size_t)(n0 + sr) * D_ + sh * 16;

  ushort8 ar2[2];
  float br[16];
  f32x4 acc[4][4];
#pragma unroll
  for (int i = 0; i < 4; ++i)
#pragma unroll
    for (int j = 0; j < 4; ++j) acc[i][j] = (f32x4){0.f, 0.f, 0.f, 0.f};

  auto ldg_tile = [&](int kt) {
    ar2[0] = *(const ushort8*)(Apb + kt * 32);
    ar2[1] = *(const ushort8*)(Apb + kt * 32 + 8);
#pragma unroll
    for (int j = 0; j < 4; ++j)
      *(f32x4*)(br + 4 * j) = *(const f32x4*)(Bpb + kt * 32 + 4 * j);
  };
  auto sts_tile = [&]() {
    *(ushort8*)&As[sr][sh * 16]     = ar2[0];
    *(ushort8*)&As[sr][sh * 16 + 8] = ar2[1];
    unsigned short tb[16];
#pragma unroll
    for (int j = 0; j < 16; ++j) tb[j] = f2bf(br[j]);
    *(ushort8*)&Bs[sr][sh * 16]     = *(ushort8*)&tb[0];
    *(ushort8*)&Bs[sr][sh * 16 + 8] = *(ushort8*)&tb[8];
  };

  ldg_tile(0);
  sts_tile();
  __syncthreads();

  for (int kt = 0; kt < 32; ++kt) {
    if (kt < 31) ldg_tile(kt + 1);
    bf16x8 af[4], bfr[4];
#pragma unroll
    for (int i = 0; i < 4; ++i) af[i]  = *(bf16x8*)&As[wr * 64 + i * 16 + c][g * 8];
#pragma unroll
    for (int i = 0; i < 4; ++i) bfr[i] = *(bf16x8*)&Bs[wc * 64 + i * 16 + c][g * 8];
#pragma unroll
    for (int mi = 0; mi < 4; ++mi)
#pragma unroll
      for (int ni = 0; ni < 4; ++ni)
        acc[mi][ni] = mfma16(af[mi], bfr[ni], acc[mi][ni]);
    __syncthreads();
    if (kt < 31) { sts_tile(); __syncthreads(); }
  }

#pragma unroll
  for (int mi = 0; mi < 4; ++mi)
#pragma unroll
    for (int ni = 0; ni < 4; ++ni)
#pragma unroll
      for (int r = 0; r < 4; ++r) {
        const int m = m0 + wr * 64 + mi * 16 + g * 4 + r;
        const int n = n0 + wc * 64 + ni * 16 + c;
        out[(size_t)m * D_ + n] = acc[mi][ni][r];
      }
}

// ---------------------------------------------------------------------------
extern "C" void kernel_launch(void* const* d_in, const int* in_sizes, int n_in,
                              void* d_out, int out_size, void* d_ws, size_t ws_size,
                              hipStream_t stream)
{
  const float* q  = (const float*)d_in[0];
  const float* k  = (const float*)d_in[1];
  const float* v  = (const float*)d_in[2];
  const float* wq = (const float*)d_in[3];
  const float* wk = (const float*)d_in[4];
  const float* wv = (const float*)d_in[5];
  const float* wo = (const float*)d_in[6];

  float* out  = (float*)d_out;
  float* attn = out + (size_t)B_ * S_ * D_;   // tuple order: (out, attn)

  const size_t NE = (size_t)B_ * S_ * D_;
  unsigned short* qh   = (unsigned short*)d_ws;
  unsigned short* kh   = qh + NE;
  unsigned short* vt   = kh + NE;
  unsigned short* comb = vt + NE;

  proj_qkv_kernel<<<dim3(8, 32, 3), dim3(256), 0, stream>>>(q, k, v, wq, wk, wv, qh, kh, vt);
  attn_kernel<<<dim3(1024), dim3(256), 0, stream>>>(qh, kh, vt, attn, comb);
  out_proj_kernel<<<dim3(8, 32), dim3(256), 0, stream>>>(comb, wo, out);
}

// Round 14
// 226.960 us; speedup vs baseline: 1.2523x; 1.0249x over previous
//
#include <hip/hip_runtime.h>
#include <hip/hip_bf16.h>
#include <cstdint>

#define B_ 2
#define S_ 2048
#define D_ 1024
#define H_ 16
#define HD_ 64

#define SCALE_LOG2 0.18033688011112042f   // (1/8) * log2(e), folded into Q proj

typedef __attribute__((ext_vector_type(8))) __bf16 bf16x8;
typedef __attribute__((ext_vector_type(8))) unsigned short ushort8;
typedef __attribute__((ext_vector_type(4))) unsigned short ushort4v;
typedef __attribute__((ext_vector_type(4))) float f32x4;

__device__ __forceinline__ unsigned short f2bf(float f) {
  __bf16 h = (__bf16)f;                       // native v_cvt (RNE)
  return __builtin_bit_cast(unsigned short, h);
}

__device__ __forceinline__ float bf2f(unsigned short u) {
  union { unsigned int i; float f; } v; v.i = ((unsigned int)u) << 16; return v.f;
}

__device__ __forceinline__ float fexp2(float x) {
#if __has_builtin(__builtin_amdgcn_exp2f)
  return __builtin_amdgcn_exp2f(x);           // raw v_exp_f32
#else
  return exp2f(x);
#endif
}

__device__ __forceinline__ f32x4 mfma16(bf16x8 a, bf16x8 b, f32x4 c) {
  return __builtin_amdgcn_mfma_f32_16x16x32_bf16(a, b, c, 0, 0, 0);
}

// LDS-hazard-only barrier: does NOT drain vmcnt, so in-flight global stores
// keep draining in the background.
#define LGKM_BARRIER()                                        \
  do {                                                        \
    asm volatile("s_waitcnt lgkmcnt(0)" ::: "memory");        \
    __builtin_amdgcn_s_barrier();                             \
  } while (0)

// 32B-granule XOR swizzle for [64][64]-short LDS tiles (keeps 16B alignment).
#define SWZ(r, sc) ((sc) ^ (((r) & 3) << 4))

// ---------------------------------------------------------------------------
// Kernel A: QKV projections. C[m][n] = sum_k X[m][k] * W[n][k]  (NT GEMM)
// z=0: Q -> qh[(b*H+h)*S + s][hd]  (PRE-SCALED by (1/8)*log2(e))
// z=1: K -> kh, same layout
// z=2: V -> vt[(b*H+h)*HD + hd][s]  (transposed for PV B-operand)
// ---------------------------------------------------------------------------
__global__ __launch_bounds__(256) void proj_qkv_kernel(
    const float* __restrict__ qin, const float* __restrict__ kin,
    const float* __restrict__ vin, const float* __restrict__ wq,
    const float* __restrict__ wk, const float* __restrict__ wv,
    unsigned short* __restrict__ qh, unsigned short* __restrict__ kh,
    unsigned short* __restrict__ vt)
{
  __shared__ unsigned short As[128][40];
  __shared__ unsigned short Bs[128][40];

  const int z = blockIdx.z;
  const float* X = (z == 0) ? qin : (z == 1) ? kin : vin;
  const float* W = (z == 0) ? wq : (z == 1) ? wk : wv;
  unsigned short* dst = (z == 0) ? qh : (z == 1) ? kh : vt;
  const float osc = (z == 0) ? SCALE_LOG2 : 1.0f;

  // bijective chunked XCD swizzle over the 256 (x,y) blocks
  const int lin = blockIdx.x + 8 * blockIdx.y;
  const int swz = (lin & 7) * 32 + (lin >> 3);
  const int bx = swz & 7, by = swz >> 3;

  const int tid = threadIdx.x;
  const int lane = tid & 63, wid = tid >> 6;
  const int c = lane & 15, g = lane >> 4;
  const int wr = wid >> 1, wc = wid & 1;           // 2x2 waves, 64x64 each
  const int m0 = by * 128, n0 = bx * 128;

  const int sr = tid >> 1, sh = tid & 1;
  const float* Ap = X + (size_t)(m0 + sr) * D_ + sh * 16;
  const float* Bp = W + (size_t)(n0 + sr) * D_ + sh * 16;

  float ar[16], br[16];
  f32x4 acc[4][4];
#pragma unroll
  for (int i = 0; i < 4; ++i)
#pragma unroll
    for (int j = 0; j < 4; ++j) acc[i][j] = (f32x4){0.f, 0.f, 0.f, 0.f};

  auto ldg_tile = [&](int kt) {
    const float* ap = Ap + kt * 32;
    const float* bp = Bp + kt * 32;
#pragma unroll
    for (int j = 0; j < 4; ++j) {
      *(f32x4*)(ar + 4 * j) = *(const f32x4*)(ap + 4 * j);
      *(f32x4*)(br + 4 * j) = *(const f32x4*)(bp + 4 * j);
    }
  };
  auto sts_tile = [&]() {
    unsigned short ta[16], tb[16];
#pragma unroll
    for (int j = 0; j < 16; ++j) { ta[j] = f2bf(ar[j]); tb[j] = f2bf(br[j]); }
    *(ushort8*)&As[sr][sh * 16]     = *(ushort8*)&ta[0];
    *(ushort8*)&As[sr][sh * 16 + 8] = *(ushort8*)&ta[8];
    *(ushort8*)&Bs[sr][sh * 16]     = *(ushort8*)&tb[0];
    *(ushort8*)&Bs[sr][sh * 16 + 8] = *(ushort8*)&tb[8];
  };

  ldg_tile(0);
  sts_tile();
  __syncthreads();

  for (int kt = 0; kt < 32; ++kt) {
    if (kt < 31) ldg_tile(kt + 1);
    bf16x8 af[4], bfr[4];
#pragma unroll
    for (int i = 0; i < 4; ++i) af[i]  = *(bf16x8*)&As[wr * 64 + i * 16 + c][g * 8];
#pragma unroll
    for (int i = 0; i < 4; ++i) bfr[i] = *(bf16x8*)&Bs[wc * 64 + i * 16 + c][g * 8];
#pragma unroll
    for (int mi = 0; mi < 4; ++mi)
#pragma unroll
      for (int ni = 0; ni < 4; ++ni)
        acc[mi][ni] = mfma16(af[mi], bfr[ni], acc[mi][ni]);
    __syncthreads();
    if (kt < 31) { sts_tile(); __syncthreads(); }
  }

#pragma unroll
  for (int mi = 0; mi < 4; ++mi) {
#pragma unroll
    for (int ni = 0; ni < 4; ++ni) {
      const int n = n0 + wc * 64 + ni * 16 + c;
      const int h = n >> 6, hd = n & 63;
      if (z < 2) {
#pragma unroll
        for (int r = 0; r < 4; ++r) {
          const int m = m0 + wr * 64 + mi * 16 + g * 4 + r;
          const int b = m >> 11, s = m & 2047;
          dst[((size_t)(b * H_ + h) * S_ + s) * HD_ + hd] = f2bf(acc[mi][ni][r] * osc);
        }
      } else {
        const int m = m0 + wr * 64 + mi * 16 + g * 4;
        const int b = m >> 11, s = m & 2047;
        ushort4v pk;
#pragma unroll
        for (int r = 0; r < 4; ++r) pk[r] = f2bf(acc[mi][ni][r]);
        *(ushort4v*)&dst[((size_t)(b * H_ + h) * HD_ + hd) * S_ + s] = pk;
      }
    }
  }
}

// ---------------------------------------------------------------------------
// Kernel B: attention, 3-SWEEP A/B FUSION. Block = 128 q-rows (A: first 64,
// B: second 64), 4 waves x 16 q per half, grid 512 (32 bh x 4 superblocks...
// 16 superblocks of 128 q), XCD-chunked bh swizzle.
//   Sweep 1: expsum(A)            -- no stores (short exposure)
//   Sweep 2: pass-2(A) + expsum(B) fused: B's QK reuses the SAME K-fragment
//            registers loaded for A (zero extra LDS traffic; +8 MFMA +16 exp
//            per wave-tile that hide under A's attn-store drain)
//   Sweep 3: pass-2(B)
// vs R7: no-store exposure per 128 q drops 2 sweeps -> 1; staging 4 -> 3.
// All R7 machinery kept: swapped QK^T (mfma(K,Q)), no-max softmax (bounded
// scores, shift-invariant => exact), scale pre-folded into Q, P->Ps bf16
// round-trip for 256B-coalesced nt f32x4 attn stores, lgkm-only barriers.
// ---------------------------------------------------------------------------
__global__ __launch_bounds__(256) void attn_kernel(
    const unsigned short* __restrict__ qh, const unsigned short* __restrict__ kh,
    const unsigned short* __restrict__ vt, float* __restrict__ attn,
    unsigned short* __restrict__ comb)
{
  __shared__ unsigned short Ks[64][64];       // K tile [k][d], SWZ-swizzled
  __shared__ unsigned short Vs[64][64];       // V^T tile [d][k], SWZ-swizzled
  __shared__ unsigned short Ps[4][16][88];    // per-wave P tile [q][k], pad 88

  const int tid = threadIdx.x;
  const int lane = tid & 63, w = tid >> 6;
  const int c = lane & 15, g = lane >> 4;

  // bijective chunked XCD swizzle: XCD r gets bh in [4r, 4r+4)
  const int lin = blockIdx.x;
  const int swz = (lin & 7) * 64 + (lin >> 3);
  const int bh = swz >> 4;
  const int q0 = (swz & 15) * 128;

  const unsigned short* Qb = qh + (size_t)bh * S_ * HD_;
  const unsigned short* Kb = kh + (size_t)bh * S_ * HD_;
  const unsigned short* Vb = vt + (size_t)bh * HD_ * S_;
  float* attnb = attn + (size_t)bh * S_ * S_;

  const int sr = tid >> 2;            // staging row 0..63
  const int scol = (tid & 3) * 16;    // 0,16,32,48
  const int swcol = SWZ(sr, scol);

  bf16x8 aQA[2], aQB[2];
#pragma unroll
  for (int t = 0; t < 2; ++t) {
    aQA[t] = *(const bf16x8*)(Qb + (size_t)(q0 + w * 16 + c) * HD_ + t * 32 + g * 8);
    aQB[t] = *(const bf16x8*)(Qb + (size_t)(q0 + 64 + w * 16 + c) * HD_ + t * 32 + g * 8);
  }

  const unsigned short* Kst = Kb + (size_t)sr * HD_ + scol;
  const unsigned short* Vst = Vb + (size_t)sr * S_ + scol;

  // ---- sweep 1: expsum(A) ----
  float lA = 0.f, lB = 0.f;
  {
    ushort8 kr0 = *(const ushort8*)Kst;
    ushort8 kr1 = *(const ushort8*)(Kst + 8);
    for (int kt = 0; kt < 32; ++kt) {
      *(ushort8*)&Ks[sr][swcol]     = kr0;
      *(ushort8*)&Ks[sr][swcol + 8] = kr1;
      LGKM_BARRIER();
      if (kt < 31) {
        const unsigned short* p = Kst + (size_t)(kt + 1) * 64 * HD_;
        kr0 = *(const ushort8*)p;
        kr1 = *(const ushort8*)(p + 8);
      }
#pragma unroll
      for (int ni = 0; ni < 4; ++ni) {
        bf16x8 k0 = *(bf16x8*)&Ks[ni * 16 + c][SWZ(c, g * 8)];
        bf16x8 k1 = *(bf16x8*)&Ks[ni * 16 + c][SWZ(c, 32 + g * 8)];
        f32x4 a = (f32x4){0.f, 0.f, 0.f, 0.f};
        a = mfma16(k0, aQA[0], a);
        a = mfma16(k1, aQA[1], a);
        lA += (fexp2(a[0]) + fexp2(a[1])) + (fexp2(a[2]) + fexp2(a[3]));
      }
      LGKM_BARRIER();
    }
  }
  lA += __shfl_xor(lA, 16);
  lA += __shfl_xor(lA, 32);
  const float invlA = 1.f / lA;

  // ---- sweep 2: pass-2(A) + expsum(B) ----
  f32x4 ctxA[4], ctxB[4];
#pragma unroll
  for (int ni = 0; ni < 4; ++ni) {
    ctxA[ni] = (f32x4){0.f, 0.f, 0.f, 0.f};
    ctxB[ni] = (f32x4){0.f, 0.f, 0.f, 0.f};
  }

  unsigned short* psrow = &Ps[w][c][g * 4];
  float* srowA = attnb + (size_t)(q0 + w * 16 + g) * S_ + c * 4;
  float* srowB = attnb + (size_t)(q0 + 64 + w * 16 + g) * S_ + c * 4;

  {
    ushort8 kr0 = *(const ushort8*)Kst;
    ushort8 kr1 = *(const ushort8*)(Kst + 8);
    ushort8 vr0 = *(const ushort8*)Vst;
    ushort8 vr1 = *(const ushort8*)(Vst + 8);

    for (int kt = 0; kt < 32; ++kt) {
      *(ushort8*)&Ks[sr][swcol]     = kr0;
      *(ushort8*)&Ks[sr][swcol + 8] = kr1;
      *(ushort8*)&Vs[sr][swcol]     = vr0;
      *(ushort8*)&Vs[sr][swcol + 8] = vr1;
      LGKM_BARRIER();
      if (kt < 31) {                     // prefetch BEFORE this tile's stores
        const unsigned short* p = Kst + (size_t)(kt + 1) * 64 * HD_;
        const unsigned short* q = Vst + (kt + 1) * 64;
        kr0 = *(const ushort8*)p;
        kr1 = *(const ushort8*)(p + 8);
        vr0 = *(const ushort8*)q;
        vr1 = *(const ushort8*)(q + 8);
      }

#pragma unroll
      for (int ni = 0; ni < 4; ++ni) {
        bf16x8 k0 = *(bf16x8*)&Ks[ni * 16 + c][SWZ(c, g * 8)];
        bf16x8 k1 = *(bf16x8*)&Ks[ni * 16 + c][SWZ(c, 32 + g * 8)];
        // A: normalized P -> Ps
        f32x4 a = (f32x4){0.f, 0.f, 0.f, 0.f};
        a = mfma16(k0, aQA[0], a);
        a = mfma16(k1, aQA[1], a);
        ushort4v pk;
#pragma unroll
        for (int r = 0; r < 4; ++r) pk[r] = f2bf(fexp2(a[r]) * invlA);
        *(ushort4v*)(psrow + ni * 16) = pk;
        // B: expsum (reuses k0/k1 -- zero extra LDS traffic)
        f32x4 b = (f32x4){0.f, 0.f, 0.f, 0.f};
        b = mfma16(k0, aQB[0], b);
        b = mfma16(k1, aQB[1], b);
        lB += (fexp2(b[0]) + fexp2(b[1])) + (fexp2(b[2]) + fexp2(b[3]));
      }

      bf16x8 aP[2];
#pragma unroll
      for (int t = 0; t < 2; ++t) aP[t] = *(bf16x8*)&Ps[w][c][t * 32 + g * 8];
#pragma unroll
      for (int ni = 0; ni < 4; ++ni)
#pragma unroll
        for (int t = 0; t < 2; ++t)
          ctxA[ni] = mfma16(aP[t],
                            *(bf16x8*)&Vs[ni * 16 + c][SWZ(c, t * 32 + g * 8)],
                            ctxA[ni]);

      // coalesced attn store for A: 4 rows x 256B contiguous
#pragma unroll
      for (int it = 0; it < 4; ++it) {
        ushort4v pb = *(ushort4v*)&Ps[w][it * 4 + g][c * 4];
        f32x4 pf;
#pragma unroll
        for (int r = 0; r < 4; ++r) pf[r] = bf2f(pb[r]);
        __builtin_nontemporal_store(pf, (f32x4*)(srowA + (size_t)it * 4 * S_ + kt * 64));
      }
      LGKM_BARRIER();
    }
  }
  lB += __shfl_xor(lB, 16);
  lB += __shfl_xor(lB, 32);
  const float invlB = 1.f / lB;

  // ---- sweep 3: pass-2(B) ----
  {
    ushort8 kr0 = *(const ushort8*)Kst;
    ushort8 kr1 = *(const ushort8*)(Kst + 8);
    ushort8 vr0 = *(const ushort8*)Vst;
    ushort8 vr1 = *(const ushort8*)(Vst + 8);

    for (int kt = 0; kt < 32; ++kt) {
      *(ushort8*)&Ks[sr][swcol]     = kr0;
      *(ushort8*)&Ks[sr][swcol + 8] = kr1;
      *(ushort8*)&Vs[sr][swcol]     = vr0;
      *(ushort8*)&Vs[sr][swcol + 8] = vr1;
      LGKM_BARRIER();
      if (kt < 31) {
        const unsigned short* p = Kst + (size_t)(kt + 1) * 64 * HD_;
        const unsigned short* q = Vst + (kt + 1) * 64;
        kr0 = *(const ushort8*)p;
        kr1 = *(const ushort8*)(p + 8);
        vr0 = *(const ushort8*)q;
        vr1 = *(const ushort8*)(q + 8);
      }

#pragma unroll
      for (int ni = 0; ni < 4; ++ni) {
        bf16x8 k0 = *(bf16x8*)&Ks[ni * 16 + c][SWZ(c, g * 8)];
        bf16x8 k1 = *(bf16x8*)&Ks[ni * 16 + c][SWZ(c, 32 + g * 8)];
        f32x4 b = (f32x4){0.f, 0.f, 0.f, 0.f};
        b = mfma16(k0, aQB[0], b);
        b = mfma16(k1, aQB[1], b);
        ushort4v pk;
#pragma unroll
        for (int r = 0; r < 4; ++r) pk[r] = f2bf(fexp2(b[r]) * invlB);
        *(ushort4v*)(psrow + ni * 16) = pk;
      }

      bf16x8 aP[2];
#pragma unroll
      for (int t = 0; t < 2; ++t) aP[t] = *(bf16x8*)&Ps[w][c][t * 32 + g * 8];
#pragma unroll
      for (int ni = 0; ni < 4; ++ni)
#pragma unroll
        for (int t = 0; t < 2; ++t)
          ctxB[ni] = mfma16(aP[t],
                            *(bf16x8*)&Vs[ni * 16 + c][SWZ(c, t * 32 + g * 8)],
                            ctxB[ni]);

#pragma unroll
      for (int it = 0; it < 4; ++it) {
        ushort4v pb = *(ushort4v*)&Ps[w][it * 4 + g][c * 4];
        f32x4 pf;
#pragma unroll
        for (int r = 0; r < 4; ++r) pf[r] = bf2f(pb[r]);
        __builtin_nontemporal_store(pf, (f32x4*)(srowB + (size_t)it * 4 * S_ + kt * 64));
      }
      LGKM_BARRIER();
    }
  }

  // epilogue: combined[b][s][h*64+d] (bf16) for A and B halves
  const int b = bh >> 4, h = bh & 15;
#pragma unroll
  for (int ni = 0; ni < 4; ++ni)
#pragma unroll
    for (int r = 0; r < 4; ++r) {
      comb[(size_t)(b * S_ + q0 + w * 16 + g * 4 + r) * D_ + h * 64 + ni * 16 + c] =
          f2bf(ctxA[ni][r]);
      comb[(size_t)(b * S_ + q0 + 64 + w * 16 + g * 4 + r) * D_ + h * 64 + ni * 16 + c] =
          f2bf(ctxB[ni][r]);
    }
}

// ---------------------------------------------------------------------------
// Kernel C: output projection. out[m][n] = sum_k comb[m][k] * wo[n][k], f32 out.
// ---------------------------------------------------------------------------
__global__ __launch_bounds__(256) void out_proj_kernel(
    const unsigned short* __restrict__ comb, const float* __restrict__ wo,
    float* __restrict__ out)
{
  __shared__ unsigned short As[128][40];
  __shared__ unsigned short Bs[128][40];

  const int lin = blockIdx.x + 8 * blockIdx.y;
  const int swz = (lin & 7) * 32 + (lin >> 3);
  const int bx = swz & 7, by = swz >> 3;

  const int tid = threadIdx.x;
  const int lane = tid & 63, wid = tid >> 6;
  const int c = lane & 15, g = lane >> 4;
  const int wr = wid >> 1, wc = wid & 1;
  const int m0 = by * 128, n0 = bx * 128;
  const int sr = tid >> 1, sh = tid & 1;

  const unsigned short* Apb = comb + (size_t)(m0 + sr) * D_ + sh * 16;
  const float* Bpb = wo + (size_t)(n0 + sr) * D_ + sh * 16;

  ushort8 ar2[2];
  float br[16];
  f32x4 acc[4][4];
#pragma unroll
  for (int i = 0; i < 4; ++i)
#pragma unroll
    for (int j = 0; j < 4; ++j) acc[i][j] = (f32x4){0.f, 0.f, 0.f, 0.f};

  auto ldg_tile = [&](int kt) {
    ar2[0] = *(const ushort8*)(Apb + kt * 32);
    ar2[1] = *(const ushort8*)(Apb + kt * 32 + 8);
#pragma unroll
    for (int j = 0; j < 4; ++j)
      *(f32x4*)(br + 4 * j) = *(const f32x4*)(Bpb + kt * 32 + 4 * j);
  };
  auto sts_tile = [&]() {
    *(ushort8*)&As[sr][sh * 16]     = ar2[0];
    *(ushort8*)&As[sr][sh * 16 + 8] = ar2[1];
    unsigned short tb[16];
#pragma unroll
    for (int j = 0; j < 16; ++j) tb[j] = f2bf(br[j]);
    *(ushort8*)&Bs[sr][sh * 16]     = *(ushort8*)&tb[0];
    *(ushort8*)&Bs[sr][sh * 16 + 8] = *(ushort8*)&tb[8];
  };

  ldg_tile(0);
  sts_tile();
  __syncthreads();

  for (int kt = 0; kt < 32; ++kt) {
    if (kt < 31) ldg_tile(kt + 1);
    bf16x8 af[4], bfr[4];
#pragma unroll
    for (int i = 0; i < 4; ++i) af[i]  = *(bf16x8*)&As[wr * 64 + i * 16 + c][g * 8];
#pragma unroll
    for (int i = 0; i < 4; ++i) bfr[i] = *(bf16x8*)&Bs[wc * 64 + i * 16 + c][g * 8];
#pragma unroll
    for (int mi = 0; mi < 4; ++mi)
#pragma unroll
      for (int ni = 0; ni < 4; ++ni)
        acc[mi][ni] = mfma16(af[mi], bfr[ni], acc[mi][ni]);
    __syncthreads();
    if (kt < 31) { sts_tile(); __syncthreads(); }
  }

#pragma unroll
  for (int mi = 0; mi < 4; ++mi)
#pragma unroll
    for (int ni = 0; ni < 4; ++ni)
#pragma unroll
      for (int r = 0; r < 4; ++r) {
        const int m = m0 + wr * 64 + mi * 16 + g * 4 + r;
        const int n = n0 + wc * 64 + ni * 16 + c;
        out[(size_t)m * D_ + n] = acc[mi][ni][r];
      }
}

// ---------------------------------------------------------------------------
extern "C" void kernel_launch(void* const* d_in, const int* in_sizes, int n_in,
                              void* d_out, int out_size, void* d_ws, size_t ws_size,
                              hipStream_t stream)
{
  const float* q  = (const float*)d_in[0];
  const float* k  = (const float*)d_in[1];
  const float* v  = (const float*)d_in[2];
  const float* wq = (const float*)d_in[3];
  const float* wk = (const float*)d_in[4];
  const float* wv = (const float*)d_in[5];
  const float* wo = (const float*)d_in[6];

  float* out  = (float*)d_out;
  float* attn = out + (size_t)B_ * S_ * D_;   // tuple order: (out, attn)

  const size_t NE = (size_t)B_ * S_ * D_;
  unsigned short* qh   = (unsigned short*)d_ws;
  unsigned short* kh   = qh + NE;
  unsigned short* vt   = kh + NE;
  unsigned short* comb = vt + NE;

  proj_qkv_kernel<<<dim3(8, 32, 3), dim3(256), 0, stream>>>(q, k, v, wq, wk, wv, qh, kh, vt);
  attn_kernel<<<dim3(512), dim3(256), 0, stream>>>(qh, kh, vt, attn, comb);
  out_proj_kernel<<<dim3(8, 32), dim3(256), 0, stream>>>(comb, wo, out);
}

// Round 15
// 209.327 us; speedup vs baseline: 1.3578x; 1.0842x over previous
//
#include <hip/hip_runtime.h>
#include <hip/hip_bf16.h>
#include <cstdint>

#define B_ 2
#define S_ 2048
#define D_ 1024
#define H_ 16
#define HD_ 64

#define SCALE_LOG2 0.18033688011112042f   // (1/8) * log2(e), folded into wq cast

typedef __attribute__((ext_vector_type(8))) __bf16 bf16x8;
typedef __attribute__((ext_vector_type(8))) unsigned short ushort8;
typedef __attribute__((ext_vector_type(4))) unsigned short ushort4v;
typedef __attribute__((ext_vector_type(4))) float f32x4;

__device__ __forceinline__ unsigned short f2bf(float f) {
  __bf16 h = (__bf16)f;                       // native v_cvt (RNE)
  return __builtin_bit_cast(unsigned short, h);
}

__device__ __forceinline__ float bf2f(unsigned short u) {
  union { unsigned int i; float f; } v; v.i = ((unsigned int)u) << 16; return v.f;
}

__device__ __forceinline__ float fexp2(float x) {
#if __has_builtin(__builtin_amdgcn_exp2f)
  return __builtin_amdgcn_exp2f(x);           // raw v_exp_f32
#else
  return exp2f(x);
#endif
}

__device__ __forceinline__ f32x4 mfma16(bf16x8 a, bf16x8 b, f32x4 c) {
  return __builtin_amdgcn_mfma_f32_16x16x32_bf16(a, b, c, 0, 0, 0);
}

// async global->LDS DMA, 16B per lane: LDS dest = wave-uniform base + lane*16
__device__ __forceinline__ void gload16(const unsigned short* g, unsigned short* l) {
  __builtin_amdgcn_global_load_lds(
      (const __attribute__((address_space(1))) unsigned int*)g,
      (__attribute__((address_space(3))) unsigned int*)l, 16, 0, 0);
}

// LDS-hazard-only barrier: does NOT drain vmcnt (attn kernel only).
#define LGKM_BARRIER()                                        \
  do {                                                        \
    asm volatile("s_waitcnt lgkmcnt(0)" ::: "memory");        \
    __builtin_amdgcn_s_barrier();                             \
  } while (0)

// 32B-granule XOR swizzle for [64][64]-short LDS tiles (keeps 16B alignment).
#define SWZ(r, sc) ((sc) ^ (((r) & 3) << 4))

// ---------------------------------------------------------------------------
// Kernel 0: f32 -> bf16 pre-cast. q,k,v,wq(*scale),wk,wv -> scratch (in the
// attn region of d_out -- dead until the attn kernel overwrites it); wo -> ws.
// 16M elems, 8/thread, fully coalesced.
// ---------------------------------------------------------------------------
__global__ __launch_bounds__(256) void cast_kernel(
    const float* __restrict__ q, const float* __restrict__ k,
    const float* __restrict__ v, const float* __restrict__ wq,
    const float* __restrict__ wk, const float* __restrict__ wv,
    const float* __restrict__ wo,
    unsigned short* __restrict__ xq, unsigned short* __restrict__ xk,
    unsigned short* __restrict__ xv, unsigned short* __restrict__ wqb,
    unsigned short* __restrict__ wkb, unsigned short* __restrict__ wvb,
    unsigned short* __restrict__ wob)
{
  const size_t M4 = (size_t)4 << 20, M1 = (size_t)1 << 20;
  size_t i = ((size_t)blockIdx.x * 256 + threadIdx.x) * 8;
  const float* src; unsigned short* dst; float sc = 1.f; size_t off;
  if (i < M4)                 { src = q;  dst = xq;  off = i; }
  else if (i < 2 * M4)        { src = k;  dst = xk;  off = i - M4; }
  else if (i < 3 * M4)        { src = v;  dst = xv;  off = i - 2 * M4; }
  else if (i < 3 * M4 + M1)   { src = wq; dst = wqb; off = i - 3 * M4; sc = SCALE_LOG2; }
  else if (i < 3 * M4 + 2*M1) { src = wk; dst = wkb; off = i - 3 * M4 - M1; }
  else if (i < 3 * M4 + 3*M1) { src = wv; dst = wvb; off = i - 3 * M4 - 2 * M1; }
  else                        { src = wo; dst = wob; off = i - 3 * M4 - 3 * M1; }
  f32x4 a = *(const f32x4*)(src + off);
  f32x4 b = *(const f32x4*)(src + off + 4);
  ushort8 o;
#pragma unroll
  for (int r = 0; r < 4; ++r) { o[r] = f2bf(a[r] * sc); o[4 + r] = f2bf(b[r] * sc); }
  *(ushort8*)(dst + off) = o;
}

// ---------------------------------------------------------------------------
// Kernel A: QKV projections, bf16 NT GEMM with global_load_lds (m97 recipe).
// C[m][n] = sum_k X[m][k] * W[n][k].  128x128 tile, BK=32, 4 waves 64x64.
// LDS: linear [128][32] bf16 (8KB) per operand; staging = 4 gload16/wave/kt.
// Swizzle (rule #21): linear LDS dest + inverse-permuted GLOBAL src slot
// (cs = (l&3) ^ ((l>>2)&3)) + XOR on read (slot = g ^ (row&3)) -> b128 reads
// are 2-lane/bank (free). z=0: Q->qh (scale pre-folded in wqb); z=1: K->kh;
// z=2: V->vt (transposed).
// ---------------------------------------------------------------------------
__global__ __launch_bounds__(256) void proj_qkv_kernel(
    const unsigned short* __restrict__ xq, const unsigned short* __restrict__ xk,
    const unsigned short* __restrict__ xv, const unsigned short* __restrict__ wqb,
    const unsigned short* __restrict__ wkb, const unsigned short* __restrict__ wvb,
    unsigned short* __restrict__ qh, unsigned short* __restrict__ kh,
    unsigned short* __restrict__ vt)
{
  __shared__ unsigned short As[128 * 32];   // linear, row = 32 bf16 (64B)
  __shared__ unsigned short Bs[128 * 32];

  const int z = blockIdx.z;
  const unsigned short* X = (z == 0) ? xq : (z == 1) ? xk : xv;
  const unsigned short* W = (z == 0) ? wqb : (z == 1) ? wkb : wvb;
  unsigned short* dst = (z == 0) ? qh : (z == 1) ? kh : vt;

  // bijective chunked XCD swizzle over the 256 (x,y) blocks
  const int lin = blockIdx.x + 8 * blockIdx.y;
  const int swz = (lin & 7) * 32 + (lin >> 3);
  const int bx = swz & 7, by = swz >> 3;

  const int tid = threadIdx.x;
  const int lane = tid & 63, w = tid >> 6;
  const int c = lane & 15, g = lane >> 4;
  const int wr = w >> 1, wc = w & 1;               // 2x2 waves, 64x64 each
  const int m0 = by * 128, n0 = bx * 128;

  // staging: wave w owns 16-row chunks {2w, 2w+1} of both A and B tiles
  const int arow = 2 * w * 16 + (lane >> 2);       // chunk 2w row
  const int cs = (lane & 3) ^ ((lane >> 2) & 3);   // inverse-permuted src slot
  const unsigned short* Asrc0 = X + (size_t)(m0 + arow) * D_ + cs * 8;
  const unsigned short* Asrc1 = Asrc0 + (size_t)16 * D_;
  const unsigned short* Bsrc0 = W + (size_t)(n0 + arow) * D_ + cs * 8;
  const unsigned short* Bsrc1 = Bsrc0 + (size_t)16 * D_;
  unsigned short* Adst0 = &As[(2 * w) * 16 * 32];      // wave-uniform bases
  unsigned short* Adst1 = &As[(2 * w + 1) * 16 * 32];
  unsigned short* Bdst0 = &Bs[(2 * w) * 16 * 32];
  unsigned short* Bdst1 = &Bs[(2 * w + 1) * 16 * 32];

  f32x4 acc[4][4];
#pragma unroll
  for (int i = 0; i < 4; ++i)
#pragma unroll
    for (int j = 0; j < 4; ++j) acc[i][j] = (f32x4){0.f, 0.f, 0.f, 0.f};

  const int rslot = 8 * 0;  // placeholder (col computed per-read below)
  (void)rslot;

  for (int kt = 0; kt < 32; ++kt) {
    gload16(Asrc0 + kt * 32, Adst0);
    gload16(Asrc1 + kt * 32, Adst1);
    gload16(Bsrc0 + kt * 32, Bdst0);
    gload16(Bsrc1 + kt * 32, Bdst1);
    __syncthreads();                       // drains vmcnt -> LDS tiles ready

    bf16x8 af[4], bfr[4];
#pragma unroll
    for (int i = 0; i < 4; ++i) {
      const int row = wr * 64 + i * 16 + c;
      af[i] = *(bf16x8*)&As[row * 32 + 8 * (g ^ (c & 3))];
    }
#pragma unroll
    for (int i = 0; i < 4; ++i) {
      const int row = wc * 64 + i * 16 + c;
      bfr[i] = *(bf16x8*)&Bs[row * 32 + 8 * (g ^ (c & 3))];
    }
#pragma unroll
    for (int mi = 0; mi < 4; ++mi)
#pragma unroll
      for (int ni = 0; ni < 4; ++ni)
        acc[mi][ni] = mfma16(af[mi], bfr[ni], acc[mi][ni]);
    __syncthreads();                       // protect LDS before next overwrite
  }

#pragma unroll
  for (int mi = 0; mi < 4; ++mi) {
#pragma unroll
    for (int ni = 0; ni < 4; ++ni) {
      const int n = n0 + wc * 64 + ni * 16 + c;
      const int h = n >> 6, hd = n & 63;
      if (z < 2) {
#pragma unroll
        for (int r = 0; r < 4; ++r) {
          const int m = m0 + wr * 64 + mi * 16 + g * 4 + r;
          const int b = m >> 11, s = m & 2047;
          dst[((size_t)(b * H_ + h) * S_ + s) * HD_ + hd] = f2bf(acc[mi][ni][r]);
        }
      } else {
        const int m = m0 + wr * 64 + mi * 16 + g * 4;
        const int b = m >> 11, s = m & 2047;
        ushort4v pk;
#pragma unroll
        for (int r = 0; r < 4; ++r) pk[r] = f2bf(acc[mi][ni][r]);
        *(ushort4v*)&dst[((size_t)(b * H_ + h) * HD_ + hd) * S_ + s] = pk;
      }
    }
  }
}

// ---------------------------------------------------------------------------
// Kernel B: attention (R14, unchanged): 3-sweep A/B fusion, swapped QK^T,
// no-max softmax, SWZ'd K/V tiles, Ps->coalesced nt f32x4 stores, lgkm-only
// barriers.
// ---------------------------------------------------------------------------
__global__ __launch_bounds__(256) void attn_kernel(
    const unsigned short* __restrict__ qh, const unsigned short* __restrict__ kh,
    const unsigned short* __restrict__ vt, float* __restrict__ attn,
    unsigned short* __restrict__ comb)
{
  __shared__ unsigned short Ks[64][64];       // K tile [k][d], SWZ-swizzled
  __shared__ unsigned short Vs[64][64];       // V^T tile [d][k], SWZ-swizzled
  __shared__ unsigned short Ps[4][16][88];    // per-wave P tile [q][k], pad 88

  const int tid = threadIdx.x;
  const int lane = tid & 63, w = tid >> 6;
  const int c = lane & 15, g = lane >> 4;

  // bijective chunked XCD swizzle: XCD r gets bh in [4r, 4r+4)
  const int lin = blockIdx.x;
  const int swz = (lin & 7) * 64 + (lin >> 3);
  const int bh = swz >> 4;
  const int q0 = (swz & 15) * 128;

  const unsigned short* Qb = qh + (size_t)bh * S_ * HD_;
  const unsigned short* Kb = kh + (size_t)bh * S_ * HD_;
  const unsigned short* Vb = vt + (size_t)bh * HD_ * S_;
  float* attnb = attn + (size_t)bh * S_ * S_;

  const int sr = tid >> 2;            // staging row 0..63
  const int scol = (tid & 3) * 16;    // 0,16,32,48
  const int swcol = SWZ(sr, scol);

  bf16x8 aQA[2], aQB[2];
#pragma unroll
  for (int t = 0; t < 2; ++t) {
    aQA[t] = *(const bf16x8*)(Qb + (size_t)(q0 + w * 16 + c) * HD_ + t * 32 + g * 8);
    aQB[t] = *(const bf16x8*)(Qb + (size_t)(q0 + 64 + w * 16 + c) * HD_ + t * 32 + g * 8);
  }

  const unsigned short* Kst = Kb + (size_t)sr * HD_ + scol;
  const unsigned short* Vst = Vb + (size_t)sr * S_ + scol;

  // ---- sweep 1: expsum(A) ----
  float lA = 0.f, lB = 0.f;
  {
    ushort8 kr0 = *(const ushort8*)Kst;
    ushort8 kr1 = *(const ushort8*)(Kst + 8);
    for (int kt = 0; kt < 32; ++kt) {
      *(ushort8*)&Ks[sr][swcol]     = kr0;
      *(ushort8*)&Ks[sr][swcol + 8] = kr1;
      LGKM_BARRIER();
      if (kt < 31) {
        const unsigned short* p = Kst + (size_t)(kt + 1) * 64 * HD_;
        kr0 = *(const ushort8*)p;
        kr1 = *(const ushort8*)(p + 8);
      }
#pragma unroll
      for (int ni = 0; ni < 4; ++ni) {
        bf16x8 k0 = *(bf16x8*)&Ks[ni * 16 + c][SWZ(c, g * 8)];
        bf16x8 k1 = *(bf16x8*)&Ks[ni * 16 + c][SWZ(c, 32 + g * 8)];
        f32x4 a = (f32x4){0.f, 0.f, 0.f, 0.f};
        a = mfma16(k0, aQA[0], a);
        a = mfma16(k1, aQA[1], a);
        lA += (fexp2(a[0]) + fexp2(a[1])) + (fexp2(a[2]) + fexp2(a[3]));
      }
      LGKM_BARRIER();
    }
  }
  lA += __shfl_xor(lA, 16);
  lA += __shfl_xor(lA, 32);
  const float invlA = 1.f / lA;

  // ---- sweep 2: pass-2(A) + expsum(B) ----
  f32x4 ctxA[4], ctxB[4];
#pragma unroll
  for (int ni = 0; ni < 4; ++ni) {
    ctxA[ni] = (f32x4){0.f, 0.f, 0.f, 0.f};
    ctxB[ni] = (f32x4){0.f, 0.f, 0.f, 0.f};
  }

  unsigned short* psrow = &Ps[w][c][g * 4];
  float* srowA = attnb + (size_t)(q0 + w * 16 + g) * S_ + c * 4;
  float* srowB = attnb + (size_t)(q0 + 64 + w * 16 + g) * S_ + c * 4;

  {
    ushort8 kr0 = *(const ushort8*)Kst;
    ushort8 kr1 = *(const ushort8*)(Kst + 8);
    ushort8 vr0 = *(const ushort8*)Vst;
    ushort8 vr1 = *(const ushort8*)(Vst + 8);

    for (int kt = 0; kt < 32; ++kt) {
      *(ushort8*)&Ks[sr][swcol]     = kr0;
      *(ushort8*)&Ks[sr][swcol + 8] = kr1;
      *(ushort8*)&Vs[sr][swcol]     = vr0;
      *(ushort8*)&Vs[sr][swcol + 8] = vr1;
      LGKM_BARRIER();
      if (kt < 31) {                     // prefetch BEFORE this tile's stores
        const unsigned short* p = Kst + (size_t)(kt + 1) * 64 * HD_;
        const unsigned short* q = Vst + (kt + 1) * 64;
        kr0 = *(const ushort8*)p;
        kr1 = *(const ushort8*)(p + 8);
        vr0 = *(const ushort8*)q;
        vr1 = *(const ushort8*)(q + 8);
      }

#pragma unroll
      for (int ni = 0; ni < 4; ++ni) {
        bf16x8 k0 = *(bf16x8*)&Ks[ni * 16 + c][SWZ(c, g * 8)];
        bf16x8 k1 = *(bf16x8*)&Ks[ni * 16 + c][SWZ(c, 32 + g * 8)];
        f32x4 a = (f32x4){0.f, 0.f, 0.f, 0.f};
        a = mfma16(k0, aQA[0], a);
        a = mfma16(k1, aQA[1], a);
        ushort4v pk;
#pragma unroll
        for (int r = 0; r < 4; ++r) pk[r] = f2bf(fexp2(a[r]) * invlA);
        *(ushort4v*)(psrow + ni * 16) = pk;
        f32x4 b = (f32x4){0.f, 0.f, 0.f, 0.f};
        b = mfma16(k0, aQB[0], b);
        b = mfma16(k1, aQB[1], b);
        lB += (fexp2(b[0]) + fexp2(b[1])) + (fexp2(b[2]) + fexp2(b[3]));
      }

      bf16x8 aP[2];
#pragma unroll
      for (int t = 0; t < 2; ++t) aP[t] = *(bf16x8*)&Ps[w][c][t * 32 + g * 8];
#pragma unroll
      for (int ni = 0; ni < 4; ++ni)
#pragma unroll
        for (int t = 0; t < 2; ++t)
          ctxA[ni] = mfma16(aP[t],
                            *(bf16x8*)&Vs[ni * 16 + c][SWZ(c, t * 32 + g * 8)],
                            ctxA[ni]);

#pragma unroll
      for (int it = 0; it < 4; ++it) {
        ushort4v pb = *(ushort4v*)&Ps[w][it * 4 + g][c * 4];
        f32x4 pf;
#pragma unroll
        for (int r = 0; r < 4; ++r) pf[r] = bf2f(pb[r]);
        __builtin_nontemporal_store(pf, (f32x4*)(srowA + (size_t)it * 4 * S_ + kt * 64));
      }
      LGKM_BARRIER();
    }
  }
  lB += __shfl_xor(lB, 16);
  lB += __shfl_xor(lB, 32);
  const float invlB = 1.f / lB;

  // ---- sweep 3: pass-2(B) ----
  {
    ushort8 kr0 = *(const ushort8*)Kst;
    ushort8 kr1 = *(const ushort8*)(Kst + 8);
    ushort8 vr0 = *(const ushort8*)Vst;
    ushort8 vr1 = *(const ushort8*)(Vst + 8);

    for (int kt = 0; kt < 32; ++kt) {
      *(ushort8*)&Ks[sr][swcol]     = kr0;
      *(ushort8*)&Ks[sr][swcol + 8] = kr1;
      *(ushort8*)&Vs[sr][swcol]     = vr0;
      *(ushort8*)&Vs[sr][swcol + 8] = vr1;
      LGKM_BARRIER();
      if (kt < 31) {
        const unsigned short* p = Kst + (size_t)(kt + 1) * 64 * HD_;
        const unsigned short* q = Vst + (kt + 1) * 64;
        kr0 = *(const ushort8*)p;
        kr1 = *(const ushort8*)(p + 8);
        vr0 = *(const ushort8*)q;
        vr1 = *(const ushort8*)(q + 8);
      }

#pragma unroll
      for (int ni = 0; ni < 4; ++ni) {
        bf16x8 k0 = *(bf16x8*)&Ks[ni * 16 + c][SWZ(c, g * 8)];
        bf16x8 k1 = *(bf16x8*)&Ks[ni * 16 + c][SWZ(c, 32 + g * 8)];
        f32x4 b = (f32x4){0.f, 0.f, 0.f, 0.f};
        b = mfma16(k0, aQB[0], b);
        b = mfma16(k1, aQB[1], b);
        ushort4v pk;
#pragma unroll
        for (int r = 0; r < 4; ++r) pk[r] = f2bf(fexp2(b[r]) * invlB);
        *(ushort4v*)(psrow + ni * 16) = pk;
      }

      bf16x8 aP[2];
#pragma unroll
      for (int t = 0; t < 2; ++t) aP[t] = *(bf16x8*)&Ps[w][c][t * 32 + g * 8];
#pragma unroll
      for (int ni = 0; ni < 4; ++ni)
#pragma unroll
        for (int t = 0; t < 2; ++t)
          ctxB[ni] = mfma16(aP[t],
                            *(bf16x8*)&Vs[ni * 16 + c][SWZ(c, t * 32 + g * 8)],
                            ctxB[ni]);

#pragma unroll
      for (int it = 0; it < 4; ++it) {
        ushort4v pb = *(ushort4v*)&Ps[w][it * 4 + g][c * 4];
        f32x4 pf;
#pragma unroll
        for (int r = 0; r < 4; ++r) pf[r] = bf2f(pb[r]);
        __builtin_nontemporal_store(pf, (f32x4*)(srowB + (size_t)it * 4 * S_ + kt * 64));
      }
      LGKM_BARRIER();
    }
  }

  const int b = bh >> 4, h = bh & 15;
#pragma unroll
  for (int ni = 0; ni < 4; ++ni)
#pragma unroll
    for (int r = 0; r < 4; ++r) {
      comb[(size_t)(b * S_ + q0 + w * 16 + g * 4 + r) * D_ + h * 64 + ni * 16 + c] =
          f2bf(ctxA[ni][r]);
      comb[(size_t)(b * S_ + q0 + 64 + w * 16 + g * 4 + r) * D_ + h * 64 + ni * 16 + c] =
          f2bf(ctxB[ni][r]);
    }
}

// ---------------------------------------------------------------------------
// Kernel C: output projection, same m97-style bf16 GEMM (A=comb, B=wob),
// f32 output.
// ---------------------------------------------------------------------------
__global__ __launch_bounds__(256) void out_proj_kernel(
    const unsigned short* __restrict__ comb, const unsigned short* __restrict__ wob,
    float* __restrict__ out)
{
  __shared__ unsigned short As[128 * 32];
  __shared__ unsigned short Bs[128 * 32];

  const int lin = blockIdx.x + 8 * blockIdx.y;
  const int swz = (lin & 7) * 32 + (lin >> 3);
  const int bx = swz & 7, by = swz >> 3;

  const int tid = threadIdx.x;
  const int lane = tid & 63, w = tid >> 6;
  const int c = lane & 15, g = lane >> 4;
  const int wr = w >> 1, wc = w & 1;
  const int m0 = by * 128, n0 = bx * 128;

  const int arow = 2 * w * 16 + (lane >> 2);
  const int cs = (lane & 3) ^ ((lane >> 2) & 3);
  const unsigned short* Asrc0 = comb + (size_t)(m0 + arow) * D_ + cs * 8;
  const unsigned short* Asrc1 = Asrc0 + (size_t)16 * D_;
  const unsigned short* Bsrc0 = wob + (size_t)(n0 + arow) * D_ + cs * 8;
  const unsigned short* Bsrc1 = Bsrc0 + (size_t)16 * D_;
  unsigned short* Adst0 = &As[(2 * w) * 16 * 32];
  unsigned short* Adst1 = &As[(2 * w + 1) * 16 * 32];
  unsigned short* Bdst0 = &Bs[(2 * w) * 16 * 32];
  unsigned short* Bdst1 = &Bs[(2 * w + 1) * 16 * 32];

  f32x4 acc[4][4];
#pragma unroll
  for (int i = 0; i < 4; ++i)
#pragma unroll
    for (int j = 0; j < 4; ++j) acc[i][j] = (f32x4){0.f, 0.f, 0.f, 0.f};

  for (int kt = 0; kt < 32; ++kt) {
    gload16(Asrc0 + kt * 32, Adst0);
    gload16(Asrc1 + kt * 32, Adst1);
    gload16(Bsrc0 + kt * 32, Bdst0);
    gload16(Bsrc1 + kt * 32, Bdst1);
    __syncthreads();

    bf16x8 af[4], bfr[4];
#pragma unroll
    for (int i = 0; i < 4; ++i) {
      const int row = wr * 64 + i * 16 + c;
      af[i] = *(bf16x8*)&As[row * 32 + 8 * (g ^ (c & 3))];
    }
#pragma unroll
    for (int i = 0; i < 4; ++i) {
      const int row = wc * 64 + i * 16 + c;
      bfr[i] = *(bf16x8*)&Bs[row * 32 + 8 * (g ^ (c & 3))];
    }
#pragma unroll
    for (int mi = 0; mi < 4; ++mi)
#pragma unroll
      for (int ni = 0; ni < 4; ++ni)
        acc[mi][ni] = mfma16(af[mi], bfr[ni], acc[mi][ni]);
    __syncthreads();
  }

#pragma unroll
  for (int mi = 0; mi < 4; ++mi)
#pragma unroll
    for (int ni = 0; ni < 4; ++ni)
#pragma unroll
      for (int r = 0; r < 4; ++r) {
        const int m = m0 + wr * 64 + mi * 16 + g * 4 + r;
        const int n = n0 + wc * 64 + ni * 16 + c;
        out[(size_t)m * D_ + n] = acc[mi][ni][r];
      }
}

// ---------------------------------------------------------------------------
extern "C" void kernel_launch(void* const* d_in, const int* in_sizes, int n_in,
                              void* d_out, int out_size, void* d_ws, size_t ws_size,
                              hipStream_t stream)
{
  const float* q  = (const float*)d_in[0];
  const float* k  = (const float*)d_in[1];
  const float* v  = (const float*)d_in[2];
  const float* wq = (const float*)d_in[3];
  const float* wk = (const float*)d_in[4];
  const float* wv = (const float*)d_in[5];
  const float* wo = (const float*)d_in[6];

  float* out  = (float*)d_out;
  float* attn = out + (size_t)B_ * S_ * D_;   // tuple order: (out, attn)

  const size_t NE = (size_t)B_ * S_ * D_;     // 4M elems
  const size_t M1 = (size_t)D_ * D_;          // 1M elems

  // bf16 scratch inside the attn region (dead until attn_kernel overwrites):
  unsigned short* scr = (unsigned short*)attn;
  unsigned short* xq  = scr;            // 4M
  unsigned short* xk  = xq + NE;        // 4M
  unsigned short* xv  = xk + NE;        // 4M
  unsigned short* wqb = xv + NE;        // 1M
  unsigned short* wkb = wqb + M1;       // 1M
  unsigned short* wvb = wkb + M1;       // 1M

  // workspace: qh,kh,vt,comb (32MB) + wob (2MB -- must survive attn_kernel)
  unsigned short* qh   = (unsigned short*)d_ws;
  unsigned short* kh   = qh + NE;
  unsigned short* vt   = kh + NE;
  unsigned short* comb = vt + NE;
  unsigned short* wob  = comb + NE;

  cast_kernel<<<dim3(8192), dim3(256), 0, stream>>>(
      q, k, v, wq, wk, wv, wo, xq, xk, xv, wqb, wkb, wvb, wob);
  proj_qkv_kernel<<<dim3(8, 32, 3), dim3(256), 0, stream>>>(
      xq, xk, xv, wqb, wkb, wvb, qh, kh, vt);
  attn_kernel<<<dim3(512), dim3(256), 0, stream>>>(qh, kh, vt, attn, comb);
  out_proj_kernel<<<dim3(8, 32), dim3(256), 0, stream>>>(comb, wob, out);
}